// Round 2
// baseline (223.560 us; speedup 1.0000x reference)
//
#include <hip/hip_runtime.h>
#include <math.h>

#define PI_F 3.14159274f        /* fp32 rounding of 3.141592653589 (== pi in fp32) */
#define STEP (5.5f/24.0f)       /* linspace(0.5, 6.0, 25) step */

constexpr int BATCH = 8;
constexpr int NATOM = 256;
constexpr int MNBR  = 100;
constexpr int NB    = 25;
constexpr int NATOT = BATCH * NATOM;   // 2048

// ---------------------------------------------------------------------------
// K1: per-atom geometry + features + rank-1 einsum -> G (2048 x 625) in d_ws
//     G[k*25 + i*5 + j] = iit[i] * H[k][j],  H[k][j] = sum_m feat[m][k]*jjt[m][j]
// ---------------------------------------------------------------------------
__global__ __launch_bounds__(256)
void k_feat(const int* __restrict__ itype, const int* __restrict__ nbr,
            const float* __restrict__ imdR, const float* __restrict__ nemb,
            float* __restrict__ gbuf)
{
    int atom = blockIdx.x;            // 0..2047
    int b    = atom >> 8;

    __shared__ float r_s[MNBR], cut_s[MNBR];
    __shared__ float jjt_s[MNBR * 5];
    __shared__ float iit_s[5];
    __shared__ float feat_s[MNBR * NB];
    __shared__ float H_s[NB * 5];

    int tid = threadIdx.x;

    if (tid < MNBR) {
        int m = tid;
        float4 v = *reinterpret_cast<const float4*>(imdR + ((size_t)atom * MNBR + m) * 4);
        float r = v.x;
        r_s[m]   = r;
        cut_s[m] = 0.5f * cosf(PI_F * r) + 0.5f;
        int j  = nbr[atom * MNBR + m];
        int tj = (j > 0) ? itype[b * NATOM + (j - 1)] : 0;
        #pragma unroll
        for (int q = 0; q < 5; q++) jjt_s[m * 5 + q] = nemb[tj * 5 + q];
    } else if (tid < MNBR + 5) {
        iit_s[tid - MNBR] = nemb[itype[atom] * 5 + (tid - MNBR)];
    }
    __syncthreads();

    // feat[m][k] = cond ? exp(-(r-rs_k)^2) * cut : 0
    for (int w = tid; w < MNBR * NB; w += 256) {
        int m = w / NB, k = w - m * NB;
        float r = r_s[m];
        float d = r - (0.5f + k * STEP);
        float g = expf(-d * d);
        float fc = (r < 6.0f && r > 0.0f) ? g * cut_s[m] : 0.0f;
        feat_s[m * NB + k] = fc;
    }
    __syncthreads();

    // H[k][j] = sum_m feat[m][k] * jjt[m][j]   (125 dot products of length 100)
    if (tid < NB * 5) {
        int k = tid / 5, j = tid - (tid / 5) * 5;
        float acc = 0.f;
        #pragma unroll 4
        for (int m = 0; m < MNBR; m++)
            acc = fmaf(feat_s[m * NB + k], jjt_s[m * 5 + j], acc);
        H_s[tid] = acc;
    }
    __syncthreads();

    // G[k*25 + i*5 + j] = iit[i] * H[k][5j]
    for (int w = tid; w < 625; w += 256) {
        int k = w / 25, e = w - k * 25;
        int i = e / 5, j = e - i * 5;
        gbuf[(size_t)atom * 625 + w] = iit_s[i] * H_s[k * 5 + j];
    }
}

// ---------------------------------------------------------------------------
// K2: MLP forward + backward for 8 atoms per block. Writes Ei, Etot (atomic),
//     and dG in-place over G in d_ws.
//     x1 phase is split-K: thread = (jo, chunk c of 125), W1 swept ONCE/block.
// ---------------------------------------------------------------------------
__global__ __launch_bounds__(512)
void k_mlp(const float* __restrict__ W1, const float* __restrict__ b1,
           const float* __restrict__ W2, const float* __restrict__ b2,
           const float* __restrict__ W3, const float* __restrict__ b3,
           const float* __restrict__ W4, const float* __restrict__ b4,
           float* __restrict__ gbuf, float* __restrict__ out)
{
    int base = blockIdx.x * 8;      // first atom of this block

    __shared__ __align__(16) float G_s[625 * 8];   // transposed: [p][atom]
    __shared__ float part_s[8 * 500];              // [atom][jo*5+c]
    __shared__ float x1_s[800], t1_s[800], x3_s[800], t3_s[800], t5_s[800];
    __shared__ float g5_s[800], g3_s[800], g1_s[800];

    int tid = threadIdx.x;

    // stage G transposed: G_s[p*8 + a] = G[atom a][p]
    for (int w = tid; w < 8 * 625; w += 512) {
        int a = w / 625, p = w - a * 625;
        G_s[p * 8 + a] = gbuf[(size_t)base * 625 + w];
    }
    __syncthreads();

    // ---- x1 = G @ W1.T + b1 : split-K. thread -> (jo = tid/5, chunk c = tid%5)
    if (tid < 500) {
        int jo = tid / 5, c = tid - (tid / 5) * 5;
        const float* wr = W1 + (size_t)jo * 625 + c * 125;
        float acc[8] = {0.f,0.f,0.f,0.f,0.f,0.f,0.f,0.f};
        for (int p = 0; p < 125; p++) {
            float w = wr[p];
            int gp = c * 125 + p;
            const float4 gA = *reinterpret_cast<const float4*>(&G_s[gp * 8]);
            const float4 gB = *reinterpret_cast<const float4*>(&G_s[gp * 8 + 4]);
            acc[0] = fmaf(w, gA.x, acc[0]);
            acc[1] = fmaf(w, gA.y, acc[1]);
            acc[2] = fmaf(w, gA.z, acc[2]);
            acc[3] = fmaf(w, gA.w, acc[3]);
            acc[4] = fmaf(w, gB.x, acc[4]);
            acc[5] = fmaf(w, gB.y, acc[5]);
            acc[6] = fmaf(w, gB.z, acc[6]);
            acc[7] = fmaf(w, gB.w, acc[7]);
        }
        #pragma unroll
        for (int a = 0; a < 8; a++)
            part_s[a * 500 + tid] = acc[a];     // coalesced LDS write
    }
    __syncthreads();

    // reduce the 5 partials, add bias, tanh
    for (int w = tid; w < 800; w += 512) {
        int a = w / 100, jo = w - (w / 100) * 100;
        const float* pp = part_s + a * 500 + jo * 5;
        float v = pp[0] + pp[1] + pp[2] + pp[3] + pp[4] + b1[jo];
        x1_s[a * 100 + jo] = v;
        t1_s[a * 100 + jo] = tanhf(v);
    }
    __syncthreads();

    // ---- x3 = tanh(x1) @ W2.T + b2 + x1 ----
    if (tid < 400) {
        int jo = tid % 100, q = tid / 100;
        int a0 = q * 2, a1 = q * 2 + 1;
        const float* wr = W2 + (size_t)jo * 100;
        float acc0 = 0.f, acc1 = 0.f;
        for (int k = 0; k < 100; k++) {
            float w = wr[k];
            acc0 = fmaf(w, t1_s[a0 * 100 + k], acc0);
            acc1 = fmaf(w, t1_s[a1 * 100 + k], acc1);
        }
        float bb = b2[jo];
        float v0 = acc0 + bb + x1_s[a0 * 100 + jo];
        float v1 = acc1 + bb + x1_s[a1 * 100 + jo];
        x3_s[a0 * 100 + jo] = v0;  t3_s[a0 * 100 + jo] = tanhf(v0);
        x3_s[a1 * 100 + jo] = v1;  t3_s[a1 * 100 + jo] = tanhf(v1);
    }
    __syncthreads();

    // ---- x5 = tanh(x3) @ W3.T + b3 + x3 ----
    if (tid < 400) {
        int jo = tid % 100, q = tid / 100;
        int a0 = q * 2, a1 = q * 2 + 1;
        const float* wr = W3 + (size_t)jo * 100;
        float acc0 = 0.f, acc1 = 0.f;
        for (int k = 0; k < 100; k++) {
            float w = wr[k];
            acc0 = fmaf(w, t3_s[a0 * 100 + k], acc0);
            acc1 = fmaf(w, t3_s[a1 * 100 + k], acc1);
        }
        float bb = b3[jo];
        float v0 = acc0 + bb + x3_s[a0 * 100 + jo];
        float v1 = acc1 + bb + x3_s[a1 * 100 + jo];
        t5_s[a0 * 100 + jo] = tanhf(v0);
        t5_s[a1 * 100 + jo] = tanhf(v1);
    }
    __syncthreads();

    // ---- Ei = t5 . W4 + b4 ; Etot += Ei  (one wave per atom) ----
    {
        int a = tid >> 6, lane = tid & 63;
        float acc = 0.f;
        for (int j = lane; j < 100; j += 64) acc += t5_s[a * 100 + j] * W4[j];
        #pragma unroll
        for (int mm = 32; mm > 0; mm >>= 1) acc += __shfl_xor(acc, mm, 64);
        if (lane == 0) {
            float ei = acc + b4[0];
            int g = base + a;
            out[8 + g] = ei;                 // Ei
            atomicAdd(&out[g >> 8], ei);     // Etot[b]
        }
    }

    // ---- g5 = W4 * (1 - t5^2) ----
    for (int w = tid; w < 800; w += 512) {
        int j = w % 100;
        float t = t5_s[w];
        g5_s[w] = W4[j] * (1.f - t * t);
    }
    __syncthreads();

    // ---- g3 = g5 + (1 - t3^2) * (g5 @ W3) ----
    if (tid < 400) {
        int k = tid % 100, q = tid / 100;
        int a0 = q * 2, a1 = q * 2 + 1;
        float acc0 = 0.f, acc1 = 0.f;
        for (int j = 0; j < 100; j++) {
            float w = W3[j * 100 + k];       // coalesced across lanes
            acc0 = fmaf(g5_s[a0 * 100 + j], w, acc0);
            acc1 = fmaf(g5_s[a1 * 100 + j], w, acc1);
        }
        float t0 = t3_s[a0 * 100 + k], t1v = t3_s[a1 * 100 + k];
        g3_s[a0 * 100 + k] = g5_s[a0 * 100 + k] + (1.f - t0 * t0) * acc0;
        g3_s[a1 * 100 + k] = g5_s[a1 * 100 + k] + (1.f - t1v * t1v) * acc1;
    }
    __syncthreads();

    // ---- g1 = g3 + (1 - t1^2) * (g3 @ W2) ----
    if (tid < 400) {
        int k = tid % 100, q = tid / 100;
        int a0 = q * 2, a1 = q * 2 + 1;
        float acc0 = 0.f, acc1 = 0.f;
        for (int j = 0; j < 100; j++) {
            float w = W2[j * 100 + k];
            acc0 = fmaf(g3_s[a0 * 100 + j], w, acc0);
            acc1 = fmaf(g3_s[a1 * 100 + j], w, acc1);
        }
        float t0 = t1_s[a0 * 100 + k], t1v = t1_s[a1 * 100 + k];
        g1_s[a0 * 100 + k] = g3_s[a0 * 100 + k] + (1.f - t0 * t0) * acc0;
        g1_s[a1 * 100 + k] = g3_s[a1 * 100 + k] + (1.f - t1v * t1v) * acc1;
    }
    __syncthreads();

    // ---- dG[p] = sum_j g1[j] * W1[j][p]  (in-place over G in d_ws) ----
    for (int p = tid; p < 625; p += 512) {
        float acc[8] = {0.f,0.f,0.f,0.f,0.f,0.f,0.f,0.f};
        for (int jo = 0; jo < 100; jo++) {
            float w = W1[(size_t)jo * 625 + p];   // coalesced across lanes
            #pragma unroll
            for (int a = 0; a < 8; a++)
                acc[a] = fmaf(w, g1_s[a * 100 + jo], acc[a]);
        }
        #pragma unroll
        for (int a = 0; a < 8; a++)
            gbuf[(size_t)(base + a) * 625 + p] = acc[a];
    }
}

// ---------------------------------------------------------------------------
// K3: backward einsums (recompute geometry) + force accumulation/scatter
// ---------------------------------------------------------------------------
__global__ __launch_bounds__(256)
void k_bwd(const int* __restrict__ itype, const int* __restrict__ nbr,
           const float* __restrict__ imdR, const float* __restrict__ nemb,
           const float* __restrict__ gbuf, float* __restrict__ out)
{
    int atom = blockIdx.x;
    int b    = atom >> 8;

    __shared__ float r_s[MNBR], cut_s[MNBR], sin_s[MNBR];
    __shared__ float jjt_s[MNBR * 5];
    __shared__ float iit_s[5];
    __shared__ float u_s[3][104];
    __shared__ int   nb_s[MNBR];
    __shared__ float dG_s[625], dH_s[125];
    __shared__ float dr_s[3][104];

    int tid = threadIdx.x;

    if (tid < MNBR) {
        int m = tid;
        float4 v = *reinterpret_cast<const float4*>(imdR + ((size_t)atom * MNBR + m) * 4);
        float r = v.x;
        r_s[m] = r;
        float sc, cc;
        sincosf(PI_F * r, &sc, &cc);
        cut_s[m] = 0.5f * cc + 0.5f;
        sin_s[m] = sc;
        float inv = (r != 0.f) ? 1.f / r : 0.f;
        u_s[0][m] = v.y * inv;
        u_s[1][m] = v.z * inv;
        u_s[2][m] = v.w * inv;
        int j = nbr[atom * MNBR + m];
        nb_s[m] = j;
        int tj = (j > 0) ? itype[b * NATOM + (j - 1)] : 0;
        #pragma unroll
        for (int q = 0; q < 5; q++) jjt_s[m * 5 + q] = nemb[tj * 5 + q];
    } else if (tid < MNBR + 5) {
        iit_s[tid - MNBR] = nemb[itype[atom] * 5 + (tid - MNBR)];
    }
    for (int w = tid; w < 625; w += 256)
        dG_s[w] = gbuf[(size_t)atom * 625 + w];
    __syncthreads();

    // dH[k][j] = sum_i iit[i] * dG[k*25 + i*5 + j]
    if (tid < 125) {
        int k = tid / 5, j = tid - (tid / 5) * 5;
        float acc = 0.f;
        #pragma unroll
        for (int i = 0; i < 5; i++)
            acc = fmaf(iit_s[i], dG_s[k * 25 + i * 5 + j], acc);
        dH_s[tid] = acc;
    }
    __syncthreads();

    // per neighbor m: s[m] = sum_k dE[m][k] * dfc[m][k] ; dE_Rid = s * unit
    if (tid < MNBR) {
        int m = tid;
        float r = r_s[m], cut = cut_s[m];
        float sterm = 0.5f * PI_F * sin_s[m];
        float j0 = jjt_s[m*5+0], j1v = jjt_s[m*5+1], j2 = jjt_s[m*5+2];
        float j3 = jjt_s[m*5+3], j4 = jjt_s[m*5+4];
        float s = 0.f;
        #pragma unroll 5
        for (int k = 0; k < NB; k++) {
            const float* dh = dH_s + k * 5;
            float dE = j0*dh[0] + j1v*dh[1] + j2*dh[2] + j3*dh[3] + j4*dh[4];
            float d  = r - (0.5f + k * STEP);
            float g  = expf(-d * d);
            float dfc = g * (-2.f * d) * cut - g * sterm;
            s = fmaf(dE, dfc, s);
        }
        if (!(r < 6.0f && r > 0.0f)) s = 0.f;
        dr_s[0][m] = s * u_s[0][m];
        dr_s[1][m] = s * u_s[1][m];
        dr_s[2][m] = s * u_s[2][m];
    }
    __syncthreads();

    // self force: Force[atom] -= sum_m dE_Rid[m]
    if (tid < 96) {
        int d = tid >> 5, g = tid & 31;
        float acc = dr_s[d][g] + dr_s[d][g + 32] + dr_s[d][g + 64];
        if (g < 4) acc += dr_s[d][g + 96];
        #pragma unroll
        for (int mm = 16; mm > 0; mm >>= 1) acc += __shfl_xor(acc, mm, 64);
        if (g == 0) atomicAdd(&out[8 + NATOT + atom * 3 + d], -acc);
    }

    // neighbor scatter: Force[j-1] += dE_Rid[m]
    if (tid < MNBR) {
        int m = tid, j = nb_s[m];
        if (j > 0) {
            int tgt = b * NATOM + (j - 1);
            atomicAdd(&out[8 + NATOT + tgt * 3 + 0], dr_s[0][m]);
            atomicAdd(&out[8 + NATOT + tgt * 3 + 1], dr_s[1][m]);
            atomicAdd(&out[8 + NATOT + tgt * 3 + 2], dr_s[2][m]);
        }
    }
}

// ---------------------------------------------------------------------------
extern "C" void kernel_launch(void* const* d_in, const int* in_sizes, int n_in,
                              void* d_out, int out_size, void* d_ws, size_t ws_size,
                              hipStream_t stream)
{
    (void)in_sizes; (void)n_in; (void)ws_size;

    const int*   itype = (const int*)  d_in[0];
    const int*   nbr   = (const int*)  d_in[1];
    const float* imdR  = (const float*)d_in[2];
    const float* nemb  = (const float*)d_in[3];
    const float* W1    = (const float*)d_in[4];
    const float* b1    = (const float*)d_in[5];
    const float* W2    = (const float*)d_in[6];
    const float* b2    = (const float*)d_in[7];
    const float* W3    = (const float*)d_in[8];
    const float* b3    = (const float*)d_in[9];
    const float* W4    = (const float*)d_in[10];
    const float* b4    = (const float*)d_in[11];

    float* out  = (float*)d_out;
    float* gbuf = (float*)d_ws;     // needs 2048*625*4 = 5.12 MB

    // out = [Etot(8) | Ei(2048) | Force(6144)] — zero for atomic accumulation
    hipMemsetAsync(d_out, 0, (size_t)out_size * sizeof(float), stream);

    hipLaunchKernelGGL(k_feat, dim3(NATOT), dim3(256), 0, stream,
                       itype, nbr, imdR, nemb, gbuf);
    hipLaunchKernelGGL(k_mlp, dim3(NATOT / 8), dim3(512), 0, stream,
                       W1, b1, W2, b2, W3, b3, W4, b4, gbuf, out);
    hipLaunchKernelGGL(k_bwd, dim3(NATOT), dim3(256), 0, stream,
                       itype, nbr, imdR, nemb, gbuf, out);
}

// Round 8
// 159.467 us; speedup vs baseline: 1.4019x; 1.4019x over previous
//
#include <hip/hip_runtime.h>
#include <math.h>

#define PI_F 3.14159274f        /* fp32 rounding of 3.141592653589 (== pi in fp32) */
#define STEP (5.5f/24.0f)       /* linspace(0.5, 6.0, 25) step */

constexpr int BATCH = 8;
constexpr int NATOM = 256;
constexpr int MNBR  = 100;
constexpr int NB    = 25;
constexpr int NATOT = BATCH * NATOM;   // 2048
constexpr int NPBLK = 256;             // k_bwd blocks (8 atoms each)

// ---------------------------------------------------------------------------
// K1: per-atom geometry + features + rank-1 einsum -> G (2048 x 625) in d_ws
//     G[k*25 + i*5 + j] = iit[i] * H[k][j],  H[k][j] = sum_m feat[m][k]*jjt[m][j]
// ---------------------------------------------------------------------------
__global__ __launch_bounds__(256)
void k_feat(const int* __restrict__ itype, const int* __restrict__ nbr,
            const float* __restrict__ imdR, const float* __restrict__ nemb,
            float* __restrict__ gbuf)
{
    int atom = blockIdx.x;            // 0..2047
    int b    = atom >> 8;

    __shared__ float r_s[MNBR], cut_s[MNBR];
    __shared__ float jjt_s[MNBR * 5];
    __shared__ float iit_s[5];
    __shared__ float feat_s[MNBR * NB];
    __shared__ float Hp_s[2][128];
    __shared__ float H_s[NB * 5];

    int tid = threadIdx.x;

    if (tid < MNBR) {
        int m = tid;
        float4 v = *reinterpret_cast<const float4*>(imdR + ((size_t)atom * MNBR + m) * 4);
        float r = v.x;
        r_s[m]   = r;
        cut_s[m] = 0.5f * cosf(PI_F * r) + 0.5f;
        int j  = nbr[atom * MNBR + m];
        int tj = (j > 0) ? itype[b * NATOM + (j - 1)] : 0;
        #pragma unroll
        for (int q = 0; q < 5; q++) jjt_s[m * 5 + q] = nemb[tj * 5 + q];
    } else if (tid < MNBR + 5) {
        iit_s[tid - MNBR] = nemb[itype[atom] * 5 + (tid - MNBR)];
    }
    __syncthreads();

    // feat[m][k] = cond ? exp(-(r-rs_k)^2) * cut : 0
    for (int w = tid; w < MNBR * NB; w += 256) {
        int m = w / NB, k = w - m * NB;
        float r = r_s[m];
        float d = r - (0.5f + k * STEP);
        float g = expf(-d * d);
        float fc = (r < 6.0f && r > 0.0f) ? g * cut_s[m] : 0.0f;
        feat_s[m * NB + k] = fc;
    }
    __syncthreads();

    // H[k][j] = sum_m feat[m][k]*jjt[m][j] — split m into 2 halves of 50
    if (tid < 250) {
        int h = tid / 125, o = tid - h * 125;
        int k = o / 5, j = o - (o / 5) * 5;
        float acc = 0.f;
        for (int m = h * 50; m < h * 50 + 50; m++)
            acc = fmaf(feat_s[m * NB + k], jjt_s[m * 5 + j], acc);
        Hp_s[h][o] = acc;
    }
    __syncthreads();
    if (tid < 125) H_s[tid] = Hp_s[0][tid] + Hp_s[1][tid];
    __syncthreads();

    // G[k*25 + i*5 + j] = iit[i] * H[k][j]
    for (int w = tid; w < 625; w += 256) {
        int k = w / 25, e = w - k * 25;
        int i = e / 5, j = e - i * 5;
        gbuf[(size_t)atom * 625 + w] = iit_s[i] * H_s[k * 5 + j];
    }
}

// ---------------------------------------------------------------------------
// K2: MLP fwd+bwd for 4 atoms/block (512 blocks -> 2 blocks/CU, 71.2 KB LDS).
//     W2/W3 staged in LDS padded [100][101] (conflict-free row & column reads).
//     x1 split-K over W1 (W1 swept once/block). Writes Ei and dG (in-place).
// ---------------------------------------------------------------------------
__global__ __launch_bounds__(512)
void k_mlp(const float* __restrict__ W1, const float* __restrict__ b1,
           const float* __restrict__ W2, const float* __restrict__ b2,
           const float* __restrict__ W3, const float* __restrict__ b3,
           const float* __restrict__ W4, const float* __restrict__ b4,
           float* __restrict__ gbuf, float* __restrict__ out)
{
    int base = blockIdx.x * 4;      // first atom of this block

    __shared__ __align__(16) float G_s[625 * 4];   // transposed: [p][atom]
    __shared__ float W_s[100 * 101];               // staged W2 or W3, padded
    __shared__ float part_s[4 * 500];              // x1 split-K partials
    __shared__ float x1_s[400], t1_s[400], x3_s[400], t3_s[400], t5_s[400];
    __shared__ float g5_s[400], g3_s[400], g1_s[400];

    int tid = threadIdx.x;

    // stage G transposed + stage W2
    for (int w = tid; w < 4 * 625; w += 512) {
        int a = w / 625, p = w - a * 625;
        G_s[p * 4 + a] = gbuf[(size_t)base * 625 + w];
    }
    for (int w = tid; w < 10000; w += 512)
        W_s[(w / 100) * 101 + (w % 100)] = W2[w];
    __syncthreads();

    // ---- x1 = G @ W1.T + b1 : split-K, thread = (jo=tid/5, chunk c=tid%5)
    if (tid < 500) {
        int jo = tid / 5, c = tid - (tid / 5) * 5;
        const float* wr = W1 + (size_t)jo * 625 + c * 125;
        float a0 = 0.f, a1 = 0.f, a2 = 0.f, a3 = 0.f;
        for (int p = 0; p < 125; p++) {
            float w = wr[p];
            float4 g = *reinterpret_cast<const float4*>(&G_s[(c * 125 + p) * 4]);
            a0 = fmaf(w, g.x, a0); a1 = fmaf(w, g.y, a1);
            a2 = fmaf(w, g.z, a2); a3 = fmaf(w, g.w, a3);
        }
        part_s[0 * 500 + tid] = a0; part_s[1 * 500 + tid] = a1;
        part_s[2 * 500 + tid] = a2; part_s[3 * 500 + tid] = a3;
    }
    __syncthreads();
    if (tid < 400) {
        int a = tid / 100, jo = tid - (tid / 100) * 100;
        const float* pp = part_s + a * 500 + jo * 5;
        float v = pp[0] + pp[1] + pp[2] + pp[3] + pp[4] + b1[jo];
        x1_s[tid] = v; t1_s[tid] = tanhf(v);
    }
    __syncthreads();

    // ---- x3 = t1 @ W2.T + b2 + x1   (W2 from LDS) ----
    if (tid < 400) {
        int a = tid / 100, jo = tid - (tid / 100) * 100;
        const float* wr = W_s + jo * 101;
        const float* tt = t1_s + a * 100;
        float acc = 0.f;
        for (int k = 0; k < 100; k++) acc = fmaf(wr[k], tt[k], acc);
        float v = acc + b2[jo] + x1_s[tid];
        x3_s[tid] = v; t3_s[tid] = tanhf(v);
    }
    __syncthreads();

    // stage W3 (overwrites W_s)
    for (int w = tid; w < 10000; w += 512)
        W_s[(w / 100) * 101 + (w % 100)] = W3[w];
    __syncthreads();

    // ---- x5 = t3 @ W3.T + b3 + x3 ----
    if (tid < 400) {
        int a = tid / 100, jo = tid - (tid / 100) * 100;
        const float* wr = W_s + jo * 101;
        const float* tt = t3_s + a * 100;
        float acc = 0.f;
        for (int k = 0; k < 100; k++) acc = fmaf(wr[k], tt[k], acc);
        float v = acc + b3[jo] + x3_s[tid];
        t5_s[tid] = tanhf(v);
    }
    __syncthreads();

    // ---- Ei = t5 . W4 + b4 (one wave per atom; no atomics) ----
    if (tid < 256) {
        int a = tid >> 6, lane = tid & 63;
        float acc = 0.f;
        for (int j = lane; j < 100; j += 64) acc += t5_s[a * 100 + j] * W4[j];
        #pragma unroll
        for (int mm = 32; mm > 0; mm >>= 1) acc += __shfl_xor(acc, mm, 64);
        if (lane == 0) out[8 + base + a] = acc + b4[0];
    }

    // ---- g5 = W4 * (1 - t5^2) ----
    if (tid < 400) {
        int jo = tid - (tid / 100) * 100;
        float t = t5_s[tid];
        g5_s[tid] = W4[jo] * (1.f - t * t);
    }
    __syncthreads();

    // ---- g3 = g5 + (1 - t3^2) * (g5 @ W3)   (W3 still in LDS) ----
    if (tid < 400) {
        int a = tid / 100, k = tid - (tid / 100) * 100;
        const float* gg = g5_s + a * 100;
        float acc = 0.f;
        for (int j = 0; j < 100; j++) acc = fmaf(gg[j], W_s[j * 101 + k], acc);
        float t = t3_s[tid];
        g3_s[tid] = g5_s[tid] + (1.f - t * t) * acc;
    }
    __syncthreads();

    // restage W2
    for (int w = tid; w < 10000; w += 512)
        W_s[(w / 100) * 101 + (w % 100)] = W2[w];
    __syncthreads();

    // ---- g1 = g3 + (1 - t1^2) * (g3 @ W2) ----
    if (tid < 400) {
        int a = tid / 100, k = tid - (tid / 100) * 100;
        const float* gg = g3_s + a * 100;
        float acc = 0.f;
        for (int j = 0; j < 100; j++) acc = fmaf(gg[j], W_s[j * 101 + k], acc);
        float t = t1_s[tid];
        g1_s[tid] = g3_s[tid] + (1.f - t * t) * acc;
    }
    __syncthreads();

    // ---- dG[p] = sum_j g1[j] * W1[j][p]  (in-place over G in d_ws) ----
    for (int p = tid; p < 625; p += 512) {
        float a0 = 0.f, a1 = 0.f, a2 = 0.f, a3 = 0.f;
        for (int jo = 0; jo < 100; jo++) {
            float w = W1[(size_t)jo * 625 + p];   // coalesced across lanes
            a0 = fmaf(w, g1_s[  0 + jo], a0);
            a1 = fmaf(w, g1_s[100 + jo], a1);
            a2 = fmaf(w, g1_s[200 + jo], a2);
            a3 = fmaf(w, g1_s[300 + jo], a3);
        }
        gbuf[(size_t)(base + 0) * 625 + p] = a0;
        gbuf[(size_t)(base + 1) * 625 + p] = a1;
        gbuf[(size_t)(base + 2) * 625 + p] = a2;
        gbuf[(size_t)(base + 3) * 625 + p] = a3;
    }
}

// ---------------------------------------------------------------------------
// K3: backward einsum + force. 8 atoms/block (1 wave/atom). Scatter goes to a
//     per-block LDS force buffer (768 floats, LDS atomics); block writes a
//     partial force array to ws (no global atomics). Fallback: global atomics.
// ---------------------------------------------------------------------------
template<bool USE_PART>
__global__ __launch_bounds__(512)
void k_bwd(const int* __restrict__ itype, const int* __restrict__ nbr,
           const float* __restrict__ imdR, const float* __restrict__ nemb,
           const float* __restrict__ gbuf, float* __restrict__ part,
           float* __restrict__ out)
{
    int bid = blockIdx.x;           // 256 blocks, 8 atoms each (same batch)
    int tid = threadIdx.x;
    int w   = tid >> 6, lane = tid & 63;
    int atom = bid * 8 + w;
    int b    = atom >> 8;

    __shared__ float dH_s[8][128];
    __shared__ float fbuf[NATOM * 3];   // per-batch force accumulator

    for (int q = tid; q < NATOM * 3; q += 512) fbuf[q] = 0.f;

    int it = itype[atom];
    float i0 = nemb[it*5+0], i1 = nemb[it*5+1], i2 = nemb[it*5+2],
          i3 = nemb[it*5+3], i4 = nemb[it*5+4];

    // dH[k][j] = sum_i iit[i] * dG[k*25 + i*5 + j]  (125 outputs per wave)
    const float* dgp = gbuf + (size_t)atom * 625;
    for (int o = lane; o < 125; o += 64) {
        int k = o / 5, j = o - (o / 5) * 5;
        const float* dg = dgp + k * 25 + j;
        dH_s[w][o] = i0*dg[0] + i1*dg[5] + i2*dg[10] + i3*dg[15] + i4*dg[20];
    }
    __syncthreads();   // fbuf zeroed + dH ready before any atomics below

    float sf0 = 0.f, sf1 = 0.f, sf2 = 0.f;
    #pragma unroll
    for (int mh = 0; mh < 2; mh++) {
        int m = lane * 2 + mh;
        if (m < MNBR) {
            float4 v = *reinterpret_cast<const float4*>(imdR + ((size_t)atom * MNBR + m) * 4);
            float r = v.x;
            float sc, cc; sincosf(PI_F * r, &sc, &cc);
            float cut = 0.5f * cc + 0.5f;
            float sterm = 0.5f * PI_F * sc;
            int j = nbr[atom * MNBR + m];
            int tj = (j > 0) ? itype[b * NATOM + (j - 1)] : 0;
            float j0 = nemb[tj*5+0], j1 = nemb[tj*5+1], j2 = nemb[tj*5+2],
                  j3 = nemb[tj*5+3], j4 = nemb[tj*5+4];
            float s = 0.f;
            for (int k = 0; k < NB; k++) {
                const float* dh = &dH_s[w][k * 5];        // broadcast reads
                float dE = j0*dh[0] + j1*dh[1] + j2*dh[2] + j3*dh[3] + j4*dh[4];
                float d  = r - (0.5f + k * STEP);
                float g  = expf(-d * d);
                float dfc = g * (-2.f * d) * cut - g * sterm;
                s = fmaf(dE, dfc, s);
            }
            if (!(r < 6.0f && r > 0.0f)) s = 0.f;
            float inv = (r != 0.f) ? 1.f / r : 0.f;
            float d0 = s * v.y * inv, d1 = s * v.z * inv, d2 = s * v.w * inv;
            sf0 += d0; sf1 += d1; sf2 += d2;
            if (j > 0) {
                atomicAdd(&fbuf[(j - 1) * 3 + 0], d0);
                atomicAdd(&fbuf[(j - 1) * 3 + 1], d1);
                atomicAdd(&fbuf[(j - 1) * 3 + 2], d2);
            }
        }
    }
    // self force: wave-reduce, subtract at own slot
    #pragma unroll
    for (int mm = 32; mm > 0; mm >>= 1) {
        sf0 += __shfl_xor(sf0, mm, 64);
        sf1 += __shfl_xor(sf1, mm, 64);
        sf2 += __shfl_xor(sf2, mm, 64);
    }
    if (lane == 0) {
        int tl = atom & 255;
        atomicAdd(&fbuf[tl * 3 + 0], -sf0);
        atomicAdd(&fbuf[tl * 3 + 1], -sf1);
        atomicAdd(&fbuf[tl * 3 + 2], -sf2);
    }
    __syncthreads();

    if (USE_PART) {
        for (int q = tid; q < NATOM * 3; q += 512)
            part[(size_t)bid * 768 + q] = fbuf[q];
    } else {
        for (int q = tid; q < NATOM * 3; q += 512) {
            float vq = fbuf[q];
            if (vq != 0.f) atomicAdd(&out[8 + NATOT + (b << 8) * 3 + q], vq);
        }
    }
}

// ---------------------------------------------------------------------------
// K4: reduce partial forces (32 per batch) + Etot from Ei. No atomics.
// ---------------------------------------------------------------------------
__global__ __launch_bounds__(256)
void k_red(const float* __restrict__ part, float* __restrict__ out, int nfblk)
{
    int bid = blockIdx.x, tid = threadIdx.x;
    if (bid < nfblk) {
        int idx = bid * 256 + tid;              // 0..6143
        int b = idx / 768, q = idx - b * 768;
        float s = 0.f;
        #pragma unroll 4
        for (int p = 0; p < 32; p++)
            s += part[(size_t)(b * 32 + p) * 768 + q];
        out[8 + NATOT + idx] = s;
    } else {
        int e = bid - nfblk;
        float v = out[8 + e * 256 + tid];       // Ei written by k_mlp
        #pragma unroll
        for (int mm = 32; mm > 0; mm >>= 1) v += __shfl_xor(v, mm, 64);
        __shared__ float ws[4];
        if ((tid & 63) == 0) ws[tid >> 6] = v;
        __syncthreads();
        if (tid == 0) out[e] = ws[0] + ws[1] + ws[2] + ws[3];
    }
}

// ---------------------------------------------------------------------------
extern "C" void kernel_launch(void* const* d_in, const int* in_sizes, int n_in,
                              void* d_out, int out_size, void* d_ws, size_t ws_size,
                              hipStream_t stream)
{
    (void)in_sizes; (void)n_in;

    const int*   itype = (const int*)  d_in[0];
    const int*   nbr   = (const int*)  d_in[1];
    const float* imdR  = (const float*)d_in[2];
    const float* nemb  = (const float*)d_in[3];
    const float* W1    = (const float*)d_in[4];
    const float* b1    = (const float*)d_in[5];
    const float* W2    = (const float*)d_in[6];
    const float* b2    = (const float*)d_in[7];
    const float* W3    = (const float*)d_in[8];
    const float* b3    = (const float*)d_in[9];
    const float* W4    = (const float*)d_in[10];
    const float* b4    = (const float*)d_in[11];

    float* out  = (float*)d_out;
    float* gbuf = (float*)d_ws;                  // 2048*625 floats
    float* part = gbuf + (size_t)NATOT * 625;    // 256*768 floats

    size_t need = ((size_t)NATOT * 625 + (size_t)NPBLK * 768) * sizeof(float);
    bool use_part = ws_size >= need;

    if (!use_part)   // fallback: zero force region for atomics
        hipMemsetAsync((char*)d_out + (size_t)(8 + NATOT) * 4, 0,
                       (size_t)NATOT * 3 * 4, stream);

    hipLaunchKernelGGL(k_feat, dim3(NATOT), dim3(256), 0, stream,
                       itype, nbr, imdR, nemb, gbuf);
    hipLaunchKernelGGL(k_mlp, dim3(NATOT / 4), dim3(512), 0, stream,
                       W1, b1, W2, b2, W3, b3, W4, b4, gbuf, out);
    if (use_part) {
        hipLaunchKernelGGL((k_bwd<true>), dim3(NPBLK), dim3(512), 0, stream,
                           itype, nbr, imdR, nemb, gbuf, part, out);
        hipLaunchKernelGGL(k_red, dim3(32), dim3(256), 0, stream, part, out, 24);
    } else {
        hipLaunchKernelGGL((k_bwd<false>), dim3(NPBLK), dim3(512), 0, stream,
                           itype, nbr, imdR, nemb, gbuf, part, out);
        hipLaunchKernelGGL(k_red, dim3(8), dim3(256), 0, stream, part, out, 0);
    }
}

// Round 10
// 131.517 us; speedup vs baseline: 1.6999x; 1.2125x over previous
//
#include <hip/hip_runtime.h>
#include <math.h>

#define PI_F 3.14159274f        /* fp32 rounding of 3.141592653589 (== pi in fp32) */
#define STEP (5.5f/24.0f)       /* linspace(0.5, 6.0, 25) step */

constexpr int BATCH = 8;
constexpr int NATOM = 256;
constexpr int MNBR  = 100;
constexpr int NB    = 25;
constexpr int NATOT = BATCH * NATOM;   // 2048
constexpr int NPBLK = 256;             // k_bwd blocks (8 atoms each)

// ws layout (float offsets). Key algebraic trick: Imagetype in {1..4} so the
// center-atom embedding iit folds into W1 per type:
//   W1t[t][jo][q]  (q = k*5+j, 125-wide)  = sum_i W1[jo][k*25+i*5+j]*nemb[t][i]
//   x1 = H @ W1t[t].T   (H is 125-wide; 625-wide G never materialized)
//   dH[q] = sum_jo g1[jo] * W1t[t][jo][q] (feeds k_bwd directly)
constexpr int OFF_W1T  = 0;                      // [5][100][125]
constexpr int OFF_W1TT = 62500;                  // [5][125][100] (transposed)
constexpr int OFF_W2T  = 125000;                 // [100][100]  W2 transposed
constexpr int OFF_W3T  = 135000;                 // [100][100]  W3 transposed
constexpr int OFF_H    = 145000;                 // [2048][125] H fwd, dH bwd (in-place)
constexpr int OFF_PART = 145000 + 2048 * 125;    // [256][768] force partials
constexpr size_t WS_NEED = (size_t)(OFF_PART + NPBLK * 768) * 4;   // ~2.39 MB

// ---------------------------------------------------------------------------
// K1: per-atom geometry + features -> H (2048 x 125) in ws.
//     Blocks 0..499 additionally build W1t/W1tT (type-folded W1); blocks
//     500..599 transpose W2/W3. All coalesced-consumable by k_mlp.
// ---------------------------------------------------------------------------
__global__ __launch_bounds__(256)
void k_feat(const int* __restrict__ itype, const int* __restrict__ nbr,
            const float* __restrict__ imdR, const float* __restrict__ nemb,
            const float* __restrict__ W1, const float* __restrict__ W2,
            const float* __restrict__ W3, float* __restrict__ ws)
{
    int atom = blockIdx.x;            // 0..2047
    int b    = atom >> 8;
    int tid  = threadIdx.x;

    // ---- folded one-time prep (tiny; hidden under per-atom latency) ----
    if (blockIdx.x < 500) {
        int t = blockIdx.x / 100, jo = blockIdx.x - (blockIdx.x / 100) * 100;
        if (tid < 125) {
            int k = tid / 5, j = tid - k * 5;
            float s = 0.f;
            #pragma unroll
            for (int i = 0; i < 5; i++)
                s = fmaf(W1[jo * 625 + k * 25 + i * 5 + j], nemb[t * 5 + i], s);
            ws[OFF_W1T  + (t * 100 + jo) * 125 + tid] = s;
            ws[OFF_W1TT + (t * 125 + tid) * 100 + jo] = s;
        }
    } else if (blockIdx.x < 600) {
        int jo = blockIdx.x - 500;
        if (tid < 100) {
            ws[OFF_W2T + tid * 100 + jo] = W2[jo * 100 + tid];
            ws[OFF_W3T + tid * 100 + jo] = W3[jo * 100 + tid];
        }
    }

    __shared__ float r_s[MNBR], cut_s[MNBR];
    __shared__ float jjt_s[MNBR * 5];
    __shared__ float feat_s[MNBR * NB];
    __shared__ float Hp_s[2][128];

    if (tid < MNBR) {
        int m = tid;
        float4 v = *reinterpret_cast<const float4*>(imdR + ((size_t)atom * MNBR + m) * 4);
        float r = v.x;
        r_s[m]   = r;
        cut_s[m] = 0.5f * cosf(PI_F * r) + 0.5f;
        int j  = nbr[atom * MNBR + m];
        int tj = (j > 0) ? itype[b * NATOM + (j - 1)] : 0;
        #pragma unroll
        for (int q = 0; q < 5; q++) jjt_s[m * 5 + q] = nemb[tj * 5 + q];
    }
    __syncthreads();

    // feat[m][k] = cond ? exp(-(r-rs_k)^2) * cut : 0
    for (int w = tid; w < MNBR * NB; w += 256) {
        int m = w / NB, k = w - m * NB;
        float r = r_s[m];
        float d = r - (0.5f + k * STEP);
        float g = expf(-d * d);
        float fc = (r < 6.0f && r > 0.0f) ? g * cut_s[m] : 0.0f;
        feat_s[m * NB + k] = fc;
    }
    __syncthreads();

    // H[k][j] = sum_m feat[m][k]*jjt[m][j] — split m into 2 halves of 50
    if (tid < 250) {
        int h = tid / 125, o = tid - h * 125;
        int k = o / 5, j = o - (o / 5) * 5;
        float acc = 0.f;
        for (int m = h * 50; m < h * 50 + 50; m++)
            acc = fmaf(feat_s[m * NB + k], jjt_s[m * 5 + j], acc);
        Hp_s[h][o] = acc;
    }
    __syncthreads();
    if (tid < 125)
        ws[OFF_H + (size_t)atom * 125 + tid] = Hp_s[0][tid] + Hp_s[1][tid];
}

// ---------------------------------------------------------------------------
// K2: MLP fwd+bwd, 4 atoms/block. All weight reads are lane-coalesced global
//     (W1tT/W2T/W3T for fwd, W2/W3/W1t for bwd) — no LDS weight staging.
//     LDS ~15 KB. Writes Ei and dH (in-place over H in ws).
// ---------------------------------------------------------------------------
__global__ __launch_bounds__(512)
void k_mlp(const int* __restrict__ itype,
           const float* __restrict__ b1, const float* __restrict__ W2,
           const float* __restrict__ b2, const float* __restrict__ W3,
           const float* __restrict__ b3, const float* __restrict__ W4,
           const float* __restrict__ b4,
           float* __restrict__ ws, float* __restrict__ out)
{
    int base = blockIdx.x * 4;
    int tid  = threadIdx.x;

    __shared__ float H_s[4 * 125];
    __shared__ float x1_s[400], t1_s[400], x3_s[400], t3_s[400], t5_s[400];
    __shared__ float g5_s[400], g3_s[400], g1_s[400];
    __shared__ int   t_s[4];

    if (tid < 4) t_s[tid] = itype[base + tid];
    if (tid < 500) H_s[tid] = ws[OFF_H + (size_t)base * 125 + tid];
    __syncthreads();

    // ---- x1 = H @ W1t[t].T + b1 ; coalesced W1tT reads ----
    if (tid < 400) {
        int a = tid / 100, jo = tid - (tid / 100) * 100;
        const float* wt = ws + OFF_W1TT + t_s[a] * 12500;   // [125][100]
        const float* hh = H_s + a * 125;
        float acc = 0.f;
        for (int q = 0; q < 125; q++)
            acc = fmaf(wt[q * 100 + jo], hh[q], acc);
        float v = acc + b1[jo];
        x1_s[tid] = v; t1_s[tid] = tanhf(v);
    }
    __syncthreads();

    // ---- x3 = t1 @ W2.T + b2 + x1 ; W2T coalesced ----
    if (tid < 400) {
        int a = tid / 100, jo = tid - (tid / 100) * 100;
        const float* wt = ws + OFF_W2T;
        const float* tt = t1_s + a * 100;
        float acc = 0.f;
        for (int k = 0; k < 100; k++) acc = fmaf(wt[k * 100 + jo], tt[k], acc);
        float v = acc + b2[jo] + x1_s[tid];
        x3_s[tid] = v; t3_s[tid] = tanhf(v);
    }
    __syncthreads();

    // ---- x5 = t3 @ W3.T + b3 + x3 ; W3T coalesced ----
    if (tid < 400) {
        int a = tid / 100, jo = tid - (tid / 100) * 100;
        const float* wt = ws + OFF_W3T;
        const float* tt = t3_s + a * 100;
        float acc = 0.f;
        for (int k = 0; k < 100; k++) acc = fmaf(wt[k * 100 + jo], tt[k], acc);
        float v = acc + b3[jo] + x3_s[tid];
        t5_s[tid] = tanhf(v);
    }
    __syncthreads();

    // ---- Ei = t5 . W4 + b4 (one wave per atom; no atomics) ----
    if (tid < 256) {
        int a = tid >> 6, lane = tid & 63;
        float acc = 0.f;
        for (int j = lane; j < 100; j += 64) acc += t5_s[a * 100 + j] * W4[j];
        #pragma unroll
        for (int mm = 32; mm > 0; mm >>= 1) acc += __shfl_xor(acc, mm, 64);
        if (lane == 0) out[8 + base + a] = acc + b4[0];
    }

    // ---- g5 = W4 * (1 - t5^2) ----
    if (tid < 400) {
        int jo = tid - (tid / 100) * 100;
        float t = t5_s[tid];
        g5_s[tid] = W4[jo] * (1.f - t * t);
    }
    __syncthreads();

    // ---- g3 = g5 + (1 - t3^2) * (g5 @ W3) ; W3 row-major coalesced ----
    if (tid < 400) {
        int a = tid / 100, k = tid - (tid / 100) * 100;
        const float* gg = g5_s + a * 100;
        float acc = 0.f;
        for (int j = 0; j < 100; j++) acc = fmaf(W3[j * 100 + k], gg[j], acc);
        float t = t3_s[tid];
        g3_s[tid] = g5_s[tid] + (1.f - t * t) * acc;
    }
    __syncthreads();

    // ---- g1 = g3 + (1 - t1^2) * (g3 @ W2) ----
    if (tid < 400) {
        int a = tid / 100, k = tid - (tid / 100) * 100;
        const float* gg = g3_s + a * 100;
        float acc = 0.f;
        for (int j = 0; j < 100; j++) acc = fmaf(W2[j * 100 + k], gg[j], acc);
        float t = t1_s[tid];
        g1_s[tid] = g3_s[tid] + (1.f - t * t) * acc;
    }
    __syncthreads();

    // ---- dH[q] = sum_jo g1[jo] * W1t[t][jo][q] ; coalesced, in-place ----
    if (tid < 500) {
        int a = tid / 125, q = tid - (tid / 125) * 125;
        const float* wt = ws + OFF_W1T + t_s[a] * 12500;    // [100][125]
        const float* gg = g1_s + a * 100;
        float acc = 0.f;
        for (int jo = 0; jo < 100; jo++)
            acc = fmaf(wt[jo * 125 + q], gg[jo], acc);
        ws[OFF_H + (size_t)(base + a) * 125 + q] = acc;
    }
}

// ---------------------------------------------------------------------------
// K3: force kernel. 8 atoms/block, 1 wave/atom. dH read directly (coalesced).
//     Scatter into per-block LDS force buffer; write partials (no glob atomics).
// ---------------------------------------------------------------------------
template<bool USE_PART>
__global__ __launch_bounds__(512)
void k_bwd(const int* __restrict__ itype, const int* __restrict__ nbr,
           const float* __restrict__ imdR, const float* __restrict__ nemb,
           float* __restrict__ ws, float* __restrict__ out)
{
    int bid = blockIdx.x;           // 256 blocks, 8 atoms each (same batch)
    int tid = threadIdx.x;
    int w   = tid >> 6, lane = tid & 63;
    int atom = bid * 8 + w;
    int b    = atom >> 8;

    __shared__ float dH_s[8][128];
    __shared__ float fbuf[NATOM * 3];   // per-batch force accumulator

    for (int q = tid; q < NATOM * 3; q += 512) fbuf[q] = 0.f;

    // dH now precomputed by k_mlp — plain coalesced load
    const float* dhp = ws + OFF_H + (size_t)atom * 125;
    for (int o = lane; o < 125; o += 64) dH_s[w][o] = dhp[o];
    __syncthreads();   // fbuf zeroed + dH ready before any atomics below

    float sf0 = 0.f, sf1 = 0.f, sf2 = 0.f;
    #pragma unroll
    for (int mh = 0; mh < 2; mh++) {
        int m = lane * 2 + mh;
        if (m < MNBR) {
            float4 v = *reinterpret_cast<const float4*>(imdR + ((size_t)atom * MNBR + m) * 4);
            float r = v.x;
            float sc, cc; sincosf(PI_F * r, &sc, &cc);
            float cut = 0.5f * cc + 0.5f;
            float sterm = 0.5f * PI_F * sc;
            int j = nbr[atom * MNBR + m];
            int tj = (j > 0) ? itype[b * NATOM + (j - 1)] : 0;
            float j0 = nemb[tj*5+0], j1 = nemb[tj*5+1], j2 = nemb[tj*5+2],
                  j3 = nemb[tj*5+3], j4 = nemb[tj*5+4];
            float s = 0.f;
            for (int k = 0; k < NB; k++) {
                const float* dh = &dH_s[w][k * 5];        // broadcast reads
                float dE = j0*dh[0] + j1*dh[1] + j2*dh[2] + j3*dh[3] + j4*dh[4];
                float d  = r - (0.5f + k * STEP);
                float g  = expf(-d * d);
                float dfc = g * (-2.f * d) * cut - g * sterm;
                s = fmaf(dE, dfc, s);
            }
            if (!(r < 6.0f && r > 0.0f)) s = 0.f;
            float inv = (r != 0.f) ? 1.f / r : 0.f;
            float d0 = s * v.y * inv, d1 = s * v.z * inv, d2 = s * v.w * inv;
            sf0 += d0; sf1 += d1; sf2 += d2;
            if (j > 0) {
                atomicAdd(&fbuf[(j - 1) * 3 + 0], d0);
                atomicAdd(&fbuf[(j - 1) * 3 + 1], d1);
                atomicAdd(&fbuf[(j - 1) * 3 + 2], d2);
            }
        }
    }
    // self force: wave-reduce, subtract at own slot
    #pragma unroll
    for (int mm = 32; mm > 0; mm >>= 1) {
        sf0 += __shfl_xor(sf0, mm, 64);
        sf1 += __shfl_xor(sf1, mm, 64);
        sf2 += __shfl_xor(sf2, mm, 64);
    }
    if (lane == 0) {
        int tl = atom & 255;
        atomicAdd(&fbuf[tl * 3 + 0], -sf0);
        atomicAdd(&fbuf[tl * 3 + 1], -sf1);
        atomicAdd(&fbuf[tl * 3 + 2], -sf2);
    }
    __syncthreads();

    if (USE_PART) {
        for (int q = tid; q < NATOM * 3; q += 512)
            ws[OFF_PART + (size_t)bid * 768 + q] = fbuf[q];
    } else {
        for (int q = tid; q < NATOM * 3; q += 512) {
            float vq = fbuf[q];
            if (vq != 0.f) atomicAdd(&out[8 + NATOT + (b << 8) * 3 + q], vq);
        }
    }
}

// ---------------------------------------------------------------------------
// K4: reduce partial forces (32 per batch) + Etot from Ei. No atomics.
// ---------------------------------------------------------------------------
__global__ __launch_bounds__(256)
void k_red(const float* __restrict__ ws, float* __restrict__ out, int nfblk)
{
    int bid = blockIdx.x, tid = threadIdx.x;
    if (bid < nfblk) {
        int idx = bid * 256 + tid;              // 0..6143
        int b = idx / 768, q = idx - b * 768;
        float s = 0.f;
        #pragma unroll 4
        for (int p = 0; p < 32; p++)
            s += ws[OFF_PART + (size_t)(b * 32 + p) * 768 + q];
        out[8 + NATOT + idx] = s;
    } else {
        int e = bid - nfblk;
        float v = out[8 + e * 256 + tid];       // Ei written by k_mlp
        #pragma unroll
        for (int mm = 32; mm > 0; mm >>= 1) v += __shfl_xor(v, mm, 64);
        __shared__ float wsum[4];
        if ((tid & 63) == 0) wsum[tid >> 6] = v;
        __syncthreads();
        if (tid == 0) out[e] = wsum[0] + wsum[1] + wsum[2] + wsum[3];
    }
}

// ---------------------------------------------------------------------------
extern "C" void kernel_launch(void* const* d_in, const int* in_sizes, int n_in,
                              void* d_out, int out_size, void* d_ws, size_t ws_size,
                              hipStream_t stream)
{
    (void)in_sizes; (void)n_in;

    const int*   itype = (const int*)  d_in[0];
    const int*   nbr   = (const int*)  d_in[1];
    const float* imdR  = (const float*)d_in[2];
    const float* nemb  = (const float*)d_in[3];
    const float* W1    = (const float*)d_in[4];
    const float* b1    = (const float*)d_in[5];
    const float* W2    = (const float*)d_in[6];
    const float* b2    = (const float*)d_in[7];
    const float* W3    = (const float*)d_in[8];
    const float* b3    = (const float*)d_in[9];
    const float* W4    = (const float*)d_in[10];
    const float* b4    = (const float*)d_in[11];

    float* out = (float*)d_out;
    float* ws  = (float*)d_ws;     // needs WS_NEED ≈ 2.39 MB (round-2 proved ≥5.12 MB)

    bool use_part = ws_size >= WS_NEED;
    if (!use_part)   // fallback: zero force region for global atomics
        hipMemsetAsync((char*)d_out + (size_t)(8 + NATOT) * 4, 0,
                       (size_t)NATOT * 3 * 4, stream);

    hipLaunchKernelGGL(k_feat, dim3(NATOT), dim3(256), 0, stream,
                       itype, nbr, imdR, nemb, W1, W2, W3, ws);
    hipLaunchKernelGGL(k_mlp, dim3(NATOT / 4), dim3(512), 0, stream,
                       itype, b1, W2, b2, W3, b3, W4, b4, ws, out);
    if (use_part) {
        hipLaunchKernelGGL((k_bwd<true>), dim3(NPBLK), dim3(512), 0, stream,
                           itype, nbr, imdR, nemb, ws, out);
        hipLaunchKernelGGL(k_red, dim3(32), dim3(256), 0, stream, ws, out, 24);
    } else {
        hipLaunchKernelGGL((k_bwd<false>), dim3(NPBLK), dim3(512), 0, stream,
                           itype, nbr, imdR, nemb, ws, out);
        hipLaunchKernelGGL(k_red, dim3(8), dim3(256), 0, stream, ws, out, 0);
    }
}